// Round 1
// baseline (31.682 us; speedup 1.0000x reference)
//
#include <hip/hip_runtime.h>
#include <hip/hip_bf16.h>
#include <math.h>

// BlockwiseDense: y[b,i,j,k] = sum_l quant(relu(cores[i,j,k,l])) * x[b, j*256+l]
// x: (128, 4096) f32, cores: (16,16,256,256) f32, out: (128,16,16,256) f32.
// One WG per (i, j, n-slice of 64 k-columns): grid = 16*16*4 = 1024 WGs, 256 thr.

typedef __attribute__((ext_vector_type(4))) float f32x4;
typedef __attribute__((ext_vector_type(8))) short bf16x8;  // 8 bf16 (4 VGPRs)
typedef __attribute__((ext_vector_type(4))) short s16x4;   // 4 bf16 (8B)

#define TAU   0.75f
#define G_INF 2.0f
#define G_MIN 0.001f

__device__ __forceinline__ short f2bf_rne(float f) {
    union { float f; unsigned u; } v; v.f = f;
    unsigned u = v.u;
    return (short)((u + 0x7FFFu + ((u >> 16) & 1u)) >> 16);
}

__global__ __launch_bounds__(256, 4)
void bd_fused(const float* __restrict__ x,
              const float* __restrict__ cores,
              float* __restrict__ out)
{
    __shared__ float levels[256];
    __shared__ unsigned char wq[64 * 512];  // 64 rows x 256 bf16, XOR-swizzled

    const int tid = threadIdx.x;

    // ---- level LUT: mirror numpy f32 op order, accurate libm expf ----
    {
        float n = (float)tid;
        float a = -TAU * n;       // f32 step-wise like np: (-tau)*n ...
        a = a / 255.0f;           // ... then / (L-1)
        float e = expf(a);
        float scale = (G_INF - G_MIN) / (1.0f - expf(-TAU));
        levels[tid] = G_MIN + scale * (1.0f - e);
    }
    __syncthreads();

    const int bid = blockIdx.x;
    const int ns = bid & 3;          // 64-column slice of k
    const int j  = (bid >> 2) & 15;  // input block
    const int i  = bid >> 6;         // output block

    const float scale     = (G_INF - G_MIN) / (1.0f - expf(-TAU));
    const float inv_scale = 1.0f / scale;
    // n(w) = -(255/tau)*ln(t) = kn * log2(t)
    const float kn = -(255.0f / TAU) * 0.69314718055994531f;

    // ---- stage + quantize W slice: rows k = ns*64 .. ns*64+63 ----
    // wsrc row r (=local k), col l: contraction dim, stride 1.
    const float* wsrc = cores + (((size_t)(i * 16 + j)) << 16) + ((size_t)ns << 14);
    #pragma unroll
    for (int it = 0; it < 16; ++it) {
        int e = it * 1024 + tid * 4;           // element index in 64x256 slice
        f32x4 v = *(const f32x4*)(wsrc + e);   // coalesced: wave covers 4KB
        s16x4 q;
        #pragma unroll
        for (int c = 0; c < 4; ++c) {
            float w = fmaxf(v[c], 0.0f);
            float t = 1.0f - (w - G_MIN) * inv_scale;  // = exp(-tau*n/255) at w
            t = fmaxf(t, 1e-20f);                      // safety (w << g_inf here)
            float nr = kn * __log2f(t);
            int f = (int)floorf(nr);
            f = f < 0 ? 0 : (f > 254 ? 254 : f);
            float lo = levels[f];
            float hi = levels[f + 1];
            // off-by-one in f only happens at a level boundary, where both
            // candidate pairs contain the true nearest level -> self-correcting.
            float qv = (w - lo < hi - w) ? lo : hi;    // same compare as reference
            q[c] = f2bf_rne(qv);
        }
        int r  = e >> 8;                 // local row (k)
        int kb = (e & 255) * 2;          // byte offset of col within row
        int off = (r * 512 + kb) ^ ((r & 7) << 4);  // bank-conflict swizzle
        *(s16x4*)(wq + off) = q;         // ds_write_b64, 2-way max (free)
    }
    __syncthreads();

    // ---- MFMA: each wave does 32 batch rows x 64 cols, K = 256 ----
    const int wave  = tid >> 6;
    const int lane  = tid & 63;
    const int l15   = lane & 15;
    const int l4    = lane >> 4;
    const int brow0 = wave * 32;

    f32x4 acc[2][4];
    #pragma unroll
    for (int mt = 0; mt < 2; ++mt)
        #pragma unroll
        for (int nt = 0; nt < 4; ++nt)
            acc[mt][nt] = (f32x4){0.f, 0.f, 0.f, 0.f};

    // A-fragment source: A[row=b][k], lane holds row=lane&15, k=(lane>>4)*8+i
    const float* xb0 = x + (size_t)(brow0 + l15) * 4096 + j * 256 + l4 * 8;

    #pragma unroll
    for (int s = 0; s < 8; ++s) {        // K steps of 32
        bf16x8 afr[2];
        #pragma unroll
        for (int mt = 0; mt < 2; ++mt) {
            const float* xp = xb0 + mt * (16 * 4096) + s * 32;
            f32x4 v0 = *(const f32x4*)xp;        // 32B/lane, 64B-coalesced/4 lanes
            f32x4 v1 = *(const f32x4*)(xp + 4);
            bf16x8 a;
            a[0] = f2bf_rne(v0[0]); a[1] = f2bf_rne(v0[1]);
            a[2] = f2bf_rne(v0[2]); a[3] = f2bf_rne(v0[3]);
            a[4] = f2bf_rne(v1[0]); a[5] = f2bf_rne(v1[1]);
            a[6] = f2bf_rne(v1[2]); a[7] = f2bf_rne(v1[3]);
            afr[mt] = a;
        }
        #pragma unroll
        for (int nt = 0; nt < 4; ++nt) {
            // B-fragment: B[k][n] = W[n][k]; lane holds n=lane&15, k=(lane>>4)*8+i
            int r   = nt * 16 + l15;
            int off = (r * 512 + s * 64 + l4 * 16) ^ ((r & 7) << 4);
            bf16x8 bfr = *(const bf16x8*)(wq + off);  // ds_read_b128, swizzled
            acc[0][nt] = __builtin_amdgcn_mfma_f32_16x16x32_bf16(afr[0], bfr, acc[0][nt], 0, 0, 0);
            acc[1][nt] = __builtin_amdgcn_mfma_f32_16x16x32_bf16(afr[1], bfr, acc[1][nt], 0, 0, 0);
        }
    }

    // ---- store: D row=(lane>>4)*4+reg, col=lane&15 (verified mapping) ----
    #pragma unroll
    for (int mt = 0; mt < 2; ++mt) {
        #pragma unroll
        for (int nt = 0; nt < 4; ++nt) {
            int k = (ns << 6) + nt * 16 + l15;
            #pragma unroll
            for (int v = 0; v < 4; ++v) {
                int b = brow0 + mt * 16 + l4 * 4 + v;
                out[((size_t)((b * 16 + i) * 16 + j) << 8) + k] = acc[mt][nt][v];
            }
        }
    }
}

extern "C" void kernel_launch(void* const* d_in, const int* in_sizes, int n_in,
                              void* d_out, int out_size, void* d_ws, size_t ws_size,
                              hipStream_t stream) {
    const float* x     = (const float*)d_in[0];
    const float* cores = (const float*)d_in[1];
    float* out = (float*)d_out;
    bd_fused<<<dim3(1024), dim3(256), 0, stream>>>(x, cores, out);
}